// Round 10
// baseline (794.824 us; speedup 1.0000x reference)
//
#include <hip/hip_runtime.h>
#include <math.h>

#define BD 8
#define CD 256
#define ND 4096
#define DA 64

typedef __attribute__((ext_vector_type(8))) short short8v;
typedef __attribute__((ext_vector_type(4))) float float4v;

static __device__ __forceinline__ float4v mfma16(short8v a, short8v b, float4v c) {
  return __builtin_amdgcn_mfma_f32_16x16x32_bf16(a, b, c, 0, 0, 0);
}
static __device__ __forceinline__ unsigned short f2bf(float f) {
  union { float f; unsigned int u; } v; v.f = f;
  return (unsigned short)((v.u + 0x7fffu + ((v.u >> 16) & 1u)) >> 16);
}
static __device__ __forceinline__ float bf2f(unsigned short h) {
  union { unsigned int u; float f; } v; v.u = (unsigned int)h << 16;
  return v.f;
}
// XOR-swizzled LDS offset (ushort units) for rows of 64 bf16 (8 x 16B chunks).
static __device__ __forceinline__ int sw(int row, int c8) {
  return row * 64 + (((c8) ^ (row & 7)) << 3);
}
typedef const __attribute__((address_space(1))) unsigned int g_u32;
typedef __attribute__((address_space(3))) unsigned int l_u32;
static __device__ __forceinline__ void gld16(const void* g, void* l) {
  __builtin_amdgcn_global_load_lds((g_u32*)g, (l_u32*)l, 16, 0, 0);
}

// ---------------------------------------------------------------------------
// k_prep: x [b][c][n] fp32 -> xTh/xTl [b][n][256] split bf16 (transposed).
// ---------------------------------------------------------------------------
__global__ __launch_bounds__(256) void k_prep(const float* __restrict__ x,
                                              unsigned short* __restrict__ xTh,
                                              unsigned short* __restrict__ xTl) {
  const int n0 = blockIdx.x * 64, c0 = blockIdx.y * 64, b = blockIdx.z;
  __shared__ float Xs[64][68];
  const int tid = threadIdx.x;
  const int r0 = tid >> 4, col4 = (tid & 15) * 4;
#pragma unroll
  for (int j = 0; j < 4; ++j) {
    int r = r0 + j * 16;
    *(float4*)&Xs[r][col4] =
        *(const float4*)&x[((size_t)(b * CD + c0 + r)) * ND + n0 + col4];
  }
  __syncthreads();
  const int n = tid >> 2, cg = (tid & 3) * 16;
  unsigned short h[16], l[16];
#pragma unroll
  for (int j = 0; j < 16; ++j) {
    float v = Xs[cg + j][n];
    h[j] = f2bf(v);
    l[j] = f2bf(v - bf2f(h[j]));
  }
  size_t o = ((size_t)b * ND + n0 + n) * CD + c0 + cg;
#pragma unroll
  for (int j = 0; j < 4; ++j) {
    *(ushort4*)&xTh[o + j * 4] = *(ushort4*)&h[j * 4];
    *(ushort4*)&xTl[o + j * 4] = *(ushort4*)&l[j * 4];
  }
}

// ---------------------------------------------------------------------------
// k_prepW: split weights fp32 -> bf16 hi/lo. Wch/Wcl = [Wq;Wk;Wv] rows 0..383.
// ---------------------------------------------------------------------------
__global__ void k_prepW(const float* __restrict__ Wq, const float* __restrict__ Wk,
                        const float* __restrict__ Wv, const float* __restrict__ Wp,
                        unsigned short* Wch, unsigned short* Wcl,
                        unsigned short* Wph, unsigned short* Wpl) {
  int i = blockIdx.x * 256 + threadIdx.x;  // 640 rows x 64 float4
  int row = i >> 6, c4 = (i & 63) * 4;
  const float* src; unsigned short *dh, *dl; int r, drow;
  if (row < 64)       { src = Wq; r = row;       dh = Wch; dl = Wcl; drow = row; }
  else if (row < 128) { src = Wk; r = row - 64;  dh = Wch; dl = Wcl; drow = row; }
  else if (row < 384) { src = Wv; r = row - 128; dh = Wch; dl = Wcl; drow = row; }
  else                { src = Wp; r = row - 384; dh = Wph; dl = Wpl; drow = row - 384; }
  float4 f = *(const float4*)&src[(size_t)r * 256 + c4];
  ushort4 hh, ll;
  hh.x = f2bf(f.x); hh.y = f2bf(f.y); hh.z = f2bf(f.z); hh.w = f2bf(f.w);
  ll.x = f2bf(f.x - bf2f(hh.x)); ll.y = f2bf(f.y - bf2f(hh.y));
  ll.z = f2bf(f.z - bf2f(hh.z)); ll.w = f2bf(f.w - bf2f(hh.w));
  *(ushort4*)&dh[(size_t)drow * 256 + c4] = hh;
  *(ushort4*)&dl[(size_t)drow * 256 + c4] = ll;
}

// ---------------------------------------------------------------------------
// k_proj: MERGED q/k/v projection (reads xT once, LDS k-slices, 3-product).
// grid (ND/128, B), 512 thr. q: hi only; k: hi+lo; v: transposed bf16.
// ---------------------------------------------------------------------------
__global__ __launch_bounds__(512) void k_proj(
    const unsigned short* __restrict__ xTh, const unsigned short* __restrict__ xTl,
    const unsigned short* __restrict__ Wch, const unsigned short* __restrict__ Wcl,
    unsigned short* __restrict__ qh, unsigned short* __restrict__ kh,
    unsigned short* __restrict__ kl, unsigned short* __restrict__ vT) {
  const int n0 = blockIdx.x * 128, b = blockIdx.y;
  const int tid = threadIdx.x, w = tid >> 6, lane = tid & 63, lq = lane & 15,
            quad = lane >> 4;
  __shared__ __align__(16) unsigned short xs[2][2][128][40];
  float4v O[24];
#pragma unroll
  for (int t = 0; t < 24; ++t) O[t] = (float4v){0.f, 0.f, 0.f, 0.f};

  const int srow = tid >> 2, sc4 = tid & 3;
  uint4 rh, rl;
  auto load_slice = [&](int ks) {
    size_t a = ((size_t)b * ND + n0 + srow) * CD + ks * 32 + sc4 * 8;
    rh = *(const uint4*)(xTh + a);
    rl = *(const uint4*)(xTl + a);
  };
  auto write_slice = [&](int buf) {
    *(uint4*)&xs[buf][0][srow][sc4 * 8] = rh;
    *(uint4*)&xs[buf][1][srow][sc4 * 8] = rl;
  };
  load_slice(0); write_slice(0);
#pragma unroll 1
  for (int ks = 0; ks < 8; ++ks) {
    __syncthreads();
    if (ks < 7) load_slice(ks + 1);
    short8v bxh = *(const short8v*)&xs[ks & 1][0][w * 16 + lq][quad * 8];
    short8v bxl = *(const short8v*)&xs[ks & 1][1][w * 16 + lq][quad * 8];
#pragma unroll
    for (int t = 0; t < 24; ++t) {
      size_t a = (size_t)(t * 16 + lq) * CD + ks * 32 + quad * 8;
      short8v awh = *(const short8v*)(Wch + a);
      short8v awl = *(const short8v*)(Wcl + a);
      O[t] = mfma16(awh, bxh, O[t]);
      O[t] = mfma16(awl, bxh, O[t]);
      O[t] = mfma16(awh, bxl, O[t]);
    }
    if (ks < 7) write_slice((ks + 1) & 1);
  }
  const int n = n0 + w * 16 + lq;
#pragma unroll
  for (int t = 0; t < 24; ++t) {
    if (t < 4) {
      ushort4 hh;
      hh.x = f2bf(O[t][0]); hh.y = f2bf(O[t][1]);
      hh.z = f2bf(O[t][2]); hh.w = f2bf(O[t][3]);
      *(ushort4*)&qh[((size_t)b * ND + n) * DA + t * 16 + quad * 4] = hh;
    } else if (t < 8) {
      ushort4 hh, ll;
      hh.x = f2bf(O[t][0]); hh.y = f2bf(O[t][1]);
      hh.z = f2bf(O[t][2]); hh.w = f2bf(O[t][3]);
      ll.x = f2bf(O[t][0] - bf2f(hh.x)); ll.y = f2bf(O[t][1] - bf2f(hh.y));
      ll.z = f2bf(O[t][2] - bf2f(hh.z)); ll.w = f2bf(O[t][3] - bf2f(hh.w));
      size_t o = ((size_t)b * ND + n) * DA + (t - 4) * 16 + quad * 4;
      *(ushort4*)&kh[o] = hh;
      *(ushort4*)&kl[o] = ll;
    } else {
#pragma unroll
      for (int r = 0; r < 4; ++r) {
        int c = (t - 8) * 16 + quad * 4 + r;
        vT[((size_t)b * CD + c) * ND + n] = f2bf(O[t][r]);
      }
    }
  }
}

// ---------------------------------------------------------------------------
// k_colsum v2 (R9): column sums of exp(e), depth-2 MFMA/exp pipeline.
// ---------------------------------------------------------------------------
__global__ __launch_bounds__(512, 4) void k_colsum(
    const unsigned short* __restrict__ qh, const unsigned short* __restrict__ khp,
    const unsigned short* __restrict__ klp, float* __restrict__ Dp) {
  const int bid = blockIdx.x, b = bid & 7, half = (bid >> 3) & 1,
            m0 = (bid >> 4) * 128;
  const int nbase = half * 2048;
  const int tid = threadIdx.x, w = tid >> 6, lane = tid & 63, lq = lane & 15,
            quad = lane >> 4;
  const int mq = w & 3, nh = w >> 2;
  __shared__ __align__(16) unsigned short qbuf[3][4096];  // 64n x 64d swizzled
  __shared__ float Cb[128];
  short8v bkh[2][2], bkl[2][2];
#pragma unroll
  for (int sub = 0; sub < 2; ++sub)
#pragma unroll
    for (int k = 0; k < 2; ++k) {
      size_t a = ((size_t)b * ND + m0 + mq * 32 + sub * 16 + lq) * DA + k * 32 + quad * 8;
      bkh[sub][k] = *(const short8v*)(khp + a);
      bkl[sub][k] = *(const short8v*)(klp + a);
    }
  const int srow = w * 8 + (lane >> 3), sck = lane & 7;
  auto stageQ = [&](int it, int qn) {
    const unsigned short* src = qh + ((size_t)b * ND + nbase + it * 64 + srow) * DA +
                                ((sck ^ (srow & 7)) << 3);
    gld16(src, &qbuf[qn][0] + (size_t)w * 512);
  };
  stageQ(0, 0);
  stageQ(1, 1);
  asm volatile("s_waitcnt vmcnt(1)\n\ts_barrier" ::: "memory");
  float cs0 = 0.f, cs1 = 0.f;
  float4v accP[2][2];
  int rc = 0, sc = 2;
#pragma unroll 1
  for (int i = 0; i < 32; ++i) {
    if (i < 30) { stageQ(i + 2, sc); sc = (sc + 1 == 3) ? 0 : sc + 1; }
    float4v accN[2][2];
#pragma unroll
    for (int s = 0; s < 2; ++s) {
      short8v ah[2];
#pragma unroll
      for (int k = 0; k < 2; ++k)
        ah[k] = *(const short8v*)&qbuf[rc][sw(nh * 32 + s * 16 + lq, k * 4 + quad)];
#pragma unroll
      for (int sub = 0; sub < 2; ++sub) {
        float4v acc = {0.f, 0.f, 0.f, 0.f};
#pragma unroll
        for (int k = 0; k < 2; ++k) {
          acc = mfma16(ah[k], bkh[sub][k], acc);
          acc = mfma16(ah[k], bkl[sub][k], acc);
        }
        accN[s][sub] = acc;
      }
    }
    if (i > 0) {
#pragma unroll
      for (int s = 0; s < 2; ++s)
#pragma unroll
        for (int sub = 0; sub < 2; ++sub) {
          float e0 = __expf(accP[s][sub][0]) + __expf(accP[s][sub][1]) +
                     __expf(accP[s][sub][2]) + __expf(accP[s][sub][3]);
          if (sub == 0) cs0 += e0; else cs1 += e0;
        }
    }
#pragma unroll
    for (int s = 0; s < 2; ++s)
#pragma unroll
      for (int sub = 0; sub < 2; ++sub) accP[s][sub] = accN[s][sub];
    rc = (rc + 1 == 3) ? 0 : rc + 1;
    if (i < 30)
      asm volatile("s_waitcnt vmcnt(1) lgkmcnt(0)\n\ts_barrier" ::: "memory");
    else
      asm volatile("s_waitcnt vmcnt(0) lgkmcnt(0)\n\ts_barrier" ::: "memory");
  }
#pragma unroll
  for (int s = 0; s < 2; ++s)
#pragma unroll
    for (int sub = 0; sub < 2; ++sub) {
      float e0 = __expf(accP[s][sub][0]) + __expf(accP[s][sub][1]) +
                 __expf(accP[s][sub][2]) + __expf(accP[s][sub][3]);
      if (sub == 0) cs0 += e0; else cs1 += e0;
    }
  cs0 += __shfl_down(cs0, 16); cs0 += __shfl_down(cs0, 32);
  cs1 += __shfl_down(cs1, 16); cs1 += __shfl_down(cs1, 32);
  if (nh == 0 && lane < 16) {
    Cb[mq * 32 + lane] = cs0;
    Cb[mq * 32 + 16 + lane] = cs1;
  }
  __syncthreads();
  if (nh == 1 && lane < 16) {
    float t0 = Cb[mq * 32 + lane] + cs0;
    float t1 = Cb[mq * 32 + 16 + lane] + cs1;
    size_t o = (size_t)half * (BD * ND) + (size_t)b * ND + m0 + mq * 32 + lane;
    Dp[o] = t0;
    Dp[o + 16] = t1;
  }
}

// combine halves: Drec = 1/(Dp0+Dp1). grid 32 x 256.
__global__ void k_rcp(const float* __restrict__ Dp, float* __restrict__ Drec) {
  int i = blockIdx.x * 256 + threadIdx.x;
  float4 a = *(const float4*)&Dp[(size_t)i * 4];
  float4 c = *(const float4*)&Dp[(size_t)(BD * ND) + (size_t)i * 4];
  float4 r;
  r.x = 1.f / (a.x + c.x); r.y = 1.f / (a.y + c.y);
  r.z = 1.f / (a.z + c.z); r.w = 1.f / (a.w + c.w);
  *(float4*)&Drec[(size_t)i * 4] = r;
}

// ---------------------------------------------------------------------------
// k_attn v10: *** m-split, 2 independent blocks/CU *** — grid 512, each block
// owns HALF the m-range (32 tiles of 64) for its 128-n q-tile, with the R9
// wave shape / per-wave work / depth-2 exp pipeline UNCHANGED. R4's 2-block
// attempt lost because it also halved per-wave work; this keeps it intact.
// To fit 2 blocks in 160KiB: vbuf triple->double (32 iters), Pb double->
// single (+barB lgkm-only), Sb aliased onto Pb after the loop. LDS = exactly
// 81920B -> 2 blocks/CU. Blocks emit fp32 O-partials + rs-partials; k_comb
// adds halves and finishes y = x - O/S.
// body(i): [kload(i+1),dr,stageV(i+1) ; expPack(i)->Pb (accP from last body)
//           ; eMFMA(i+1)->accP ; barA(vmcnt(4),lgkm0) ; PV(i) reads
//           Pb+vbuf[i&1] ; barB(lgkm0)].
// vmcnt(4) at barA: stage(i+1)=4 newest stay in flight (consumed body i+1);
// stage(i)/kload retired by eMFMA's implicit kc wait. Numerics: fp32 partial
// reorder only.
// ---------------------------------------------------------------------------
__global__ __launch_bounds__(512, 4) void k_attn(
    const unsigned short* __restrict__ qh, const unsigned short* __restrict__ khp,
    const unsigned short* __restrict__ klp, const unsigned short* __restrict__ vT,
    const float* __restrict__ Drec, float* __restrict__ Oa,
    float* __restrict__ Rs) {
  const int bid = blockIdx.x, b = bid & 7, nt = (bid >> 3) & 31, mhalf = bid >> 8;
  const int n0 = nt * 128, mbase = mhalf * 32;  // m-tile base (tiles of 64)
  const int tid = threadIdx.x, w = tid >> 6, lane = tid & 63, lq = lane & 15,
            quad = lane >> 4;
  const int nh = w & 1, mt = w >> 1;  // 2 n-halves x 4 m/c-quarters
  __shared__ __align__(16) unsigned char ldsraw[81920];
  unsigned short* vbuf = (unsigned short*)ldsraw;            // [2][16384] 256c x 64m swz
  unsigned short* Pb = (unsigned short*)(ldsraw + 65536);    // [8192] 128n x 64m swz

  // q B-frags (hi only), resident: wave's 64-n half
  short8v aq[4][2];
#pragma unroll
  for (int s = 0; s < 4; ++s)
#pragma unroll
    for (int k = 0; k < 2; ++k)
      aq[s][k] = *(const short8v*)(qh + ((size_t)b * ND + n0 + nh * 64 + s * 16 + lq) * DA +
                                   k * 32 + quad * 8);
  float4v O[4][4];  // [ct][s]
#pragma unroll
  for (int ct = 0; ct < 4; ++ct)
#pragma unroll
    for (int s = 0; s < 4; ++s) O[ct][s] = (float4v){0.f, 0.f, 0.f, 0.f};
  float rs[4] = {0.f, 0.f, 0.f, 0.f};

  // async vT staging: 2048 chunks, 4/thread, swizzle baked into source
  auto stageV = [&](int it, int vn) {
    unsigned short* base = vbuf + (size_t)vn * 16384;
#pragma unroll
    for (int j = 0; j < 4; ++j) {
      int cidx = tid + j * 512;
      int row = cidx >> 3, ckpos = cidx & 7;
      const unsigned short* src =
          vT + ((size_t)b * CD + row) * ND + (mbase + it) * 64 + ((ckpos ^ (row & 7)) << 3);
      gld16(src, base + (size_t)(w * 64 + j * 512) * 8);
    }
  };
  short8v kc[4];  // [k*2 + (h|l)]; wave's 16 K-rows = m-quarter mt (in-place)
  auto kload = [&](int it) {
#pragma unroll
    for (int k = 0; k < 2; ++k) {
      size_t a = ((size_t)b * ND + (mbase + it) * 64 + mt * 16 + lq) * DA + k * 32 + quad * 8;
      kc[k * 2 + 0] = *(const short8v*)(khp + a);
      kc[k * 2 + 1] = *(const short8v*)(klp + a);
    }
  };
  auto doPV = [&](const unsigned short* vc) {
#pragma unroll
    for (int ks = 0; ks < 2; ++ks) {
      short8v ap[4];
#pragma unroll
      for (int s = 0; s < 4; ++s)
        ap[s] = *(const short8v*)&Pb[sw(nh * 64 + s * 16 + lq, ks * 4 + quad)];
#pragma unroll
      for (int ct = 0; ct < 4; ++ct) {
        const int trow = (mt * 4 + ct) * 16 + lq;
        short8v bv = *(const short8v*)&vc[sw(trow, ks * 4 + quad)];
#pragma unroll
        for (int s = 0; s < 4; ++s) O[ct][s] = mfma16(bv, ap[s], O[ct][s]);
      }
    }
  };
  auto eMFMA = [&](float4v* dst) {
#pragma unroll
    for (int s = 0; s < 4; ++s) {
      float4v acc = {0.f, 0.f, 0.f, 0.f};
#pragma unroll
      for (int k = 0; k < 2; ++k) {
        acc = mfma16(kc[k * 2 + 0], aq[s][k], acc);
        acc = mfma16(kc[k * 2 + 1], aq[s][k], acc);
      }
      dst[s] = acc;
    }
  };

  float4 drc4, drn4;
  stageV(0, 0);
  kload(0);
  drc4 = *(const float4*)&Drec[(size_t)b * ND + (mbase + 0) * 64 + mt * 16 + quad * 4];
  float4v accP[4];
  eMFMA(accP);  // E(0); compiler waits on kc loads

#pragma unroll 1
  for (int i = 0; i < 32; ++i) {
    if (i < 31) {
      kload(i + 1);  // in-place: kc's last read was eMFMA at end of prev body
      drn4 = *(const float4*)&Drec[(size_t)b * ND + (mbase + i + 1) * 64 + mt * 16 + quad * 4];
      stageV(i + 1, (i + 1) & 1);
    }
    // ---- expPack(i): accP ready at body start; overlaps eMFMA below ----
#pragma unroll
    for (int s = 0; s < 4; ++s) {
      float p0 = __expf(accP[s][0]) * drc4.x;
      float p1 = __expf(accP[s][1]) * drc4.y;
      float p2 = __expf(accP[s][2]) * drc4.z;
      float p3 = __expf(accP[s][3]) * drc4.w;
      rs[s] += (p0 + p1) + (p2 + p3);
      unsigned int w0 =
          (__float_as_uint(p0) >> 16) | (__float_as_uint(p1) & 0xffff0000u);
      unsigned int w1 =
          (__float_as_uint(p2) >> 16) | (__float_as_uint(p3) & 0xffff0000u);
      const int nl = nh * 64 + s * 16 + lq;
      const int c8 = mt * 2 + (quad >> 1);
      uint2 wv; wv.x = w0; wv.y = w1;
      *(uint2*)&Pb[nl * 64 + ((c8 ^ (nl & 7)) << 3) + ((quad & 1) << 2)] = wv;
    }
    if (i < 31) {
      eMFMA(accP);  // E(i+1) from the kc loaded this body
      drc4 = drn4;
    }
    // barA: Pb(i) visible; stage(i) retired (older); stage(i+1) in flight
    if (i < 31)
      asm volatile("s_waitcnt vmcnt(4) lgkmcnt(0)\n\ts_barrier" ::: "memory");
    else
      asm volatile("s_waitcnt vmcnt(0) lgkmcnt(0)\n\ts_barrier" ::: "memory");
    doPV(vbuf + (size_t)(i & 1) * 16384);
    // barB: PV's LDS reads done before next expPack rewrites Pb / next
    // body's stage(i+2) DMA rewrites vbuf[i&1]
    if (i < 31)
      asm volatile("s_waitcnt lgkmcnt(0)\n\ts_barrier" ::: "memory");
  }

  // ---- rs partial: butterfly over quad, 4-way mt combine in LDS ----
#pragma unroll
  for (int s = 0; s < 4; ++s) {
    rs[s] += __shfl_xor(rs[s], 16);
    rs[s] += __shfl_xor(rs[s], 32);
  }
  __syncthreads();  // PV(31) reads of Pb done -> safe to alias Sb onto Pb
  float* Sb = (float*)Pb;  // [4][128]
  if (lane < 16) {
#pragma unroll
    for (int s = 0; s < 4; ++s) Sb[mt * 128 + nh * 64 + s * 16 + lane] = rs[s];
  }
  __syncthreads();
  if (mt == 0 && lane < 16) {
#pragma unroll
    for (int s = 0; s < 4; ++s) {
      const int nl = nh * 64 + s * 16 + lane;
      float tot = Sb[nl] + Sb[128 + nl] + Sb[256 + nl] + Sb[384 + nl];
      Rs[((size_t)mhalf * BD + b) * ND + n0 + nl] = tot;
    }
  }
  // ---- O partial write (fp32), combined in k_comb ----
#pragma unroll
  for (int ct = 0; ct < 4; ++ct) {
#pragma unroll
    for (int s = 0; s < 4; ++s) {
      const int n = n0 + nh * 64 + s * 16 + lq;
      const int c = (mt * 4 + ct) * 16 + quad * 4;
      float4 v;
      v.x = O[ct][s][0]; v.y = O[ct][s][1]; v.z = O[ct][s][2]; v.w = O[ct][s][3];
      *(float4*)&Oa[(((size_t)mhalf * BD + b) * ND + n) * CD + c] = v;
    }
  }
}

// ---------------------------------------------------------------------------
// k_comb: y = x - (O0+O1)/(rs0+rs1), in place over xhy. Memory-bound.
// grid 8192 x 256 (one thread = 4 consecutive c of one (b,n)).
// ---------------------------------------------------------------------------
__global__ __launch_bounds__(256) void k_comb(const float* __restrict__ Oa,
                                              const float* __restrict__ Rs,
                                              unsigned short* __restrict__ xhy,
                                              const unsigned short* __restrict__ xTl) {
  const int idx = blockIdx.x * 256 + threadIdx.x;  // 8*4096*64
  const int c4 = (idx & 63) * 4;
  const int n = (idx >> 6) & (ND - 1);
  const int b = idx >> 18;
  const size_t bn = (size_t)b * ND + n;
  float4 a = *(const float4*)&Oa[bn * CD + c4];
  float4 c = *(const float4*)&Oa[((size_t)BD * ND + bn) * CD + c4];
  const float rsc = 1.0f / (1e-9f + Rs[bn] + Rs[(size_t)BD * ND + bn]);
  const size_t off = bn * CD + c4;
  ushort4 h4 = *(const ushort4*)&xhy[off];
  ushort4 l4 = *(const ushort4*)&xTl[off];
  ushort4 o4;
  o4.x = f2bf(bf2f(h4.x) + bf2f(l4.x) - (a.x + c.x) * rsc);
  o4.y = f2bf(bf2f(h4.y) + bf2f(l4.y) - (a.y + c.y) * rsc);
  o4.z = f2bf(bf2f(h4.z) + bf2f(l4.z) - (a.z + c.z) * rsc);
  o4.w = f2bf(bf2f(h4.w) + bf2f(l4.w) - (a.w + c.w) * rsc);
  *(ushort4*)&xhy[off] = o4;
}

// ---------------------------------------------------------------------------
// k_final: h = Wp . y (bf16 MFMA); out = relu(BN(h)) + x.
// ---------------------------------------------------------------------------
__global__ __launch_bounds__(256) void k_final(const unsigned short* __restrict__ y,
                                               const unsigned short* __restrict__ Wpb,
                                               const float* __restrict__ x,
                                               const float* __restrict__ gamma,
                                               const float* __restrict__ beta,
                                               const float* __restrict__ mean,
                                               const float* __restrict__ var,
                                               float* __restrict__ out) {
  const int bid = blockIdx.x;
  const int b = bid & 7;
  const int rem = bid >> 3;
  const int n0 = (rem & 63) * 64;
  const int d0 = (rem >> 6) * 64;
  const int tid = threadIdx.x;
  const int wave = tid >> 6, lane = tid & 63, lq = lane & 15, quad = lane >> 4;
  const int dw = d0 + wave * 16;
  float4v O[4];
#pragma unroll
  for (int s = 0; s < 4; ++s) O[s] = (float4v){0.f, 0.f, 0.f, 0.f};
#pragma unroll
  for (int chh = 0; chh < 8; ++chh) {
    const size_t ab = (size_t)(dw + lq) * CD + chh * 32 + quad * 8;
    short8v a0 = *(const short8v*)(Wpb + ab);
#pragma unroll
    for (int s = 0; s < 4; ++s) {
      const size_t bb = ((size_t)b * ND + n0 + s * 16 + lq) * CD + chh * 32 + quad * 8;
      short8v bv = *(const short8v*)(y + bb);
      O[s] = mfma16(a0, bv, O[s]);
    }
  }
#pragma unroll
  for (int r = 0; r < 4; ++r) {
    const int d = dw + quad * 4 + r;
    const float inv  = gamma[d] / sqrtf(var[d] + 1e-5f);
    const float bias = beta[d] - mean[d] * inv;
#pragma unroll
    for (int s = 0; s < 4; ++s) {
      const int n = n0 + s * 16 + lq;
      const size_t oi = ((size_t)b * CD + d) * ND + n;
      out[oi] = fmaxf(O[s][r] * inv + bias, 0.f) + x[oi];
    }
  }
}

extern "C" void kernel_launch(void* const* d_in, const int* in_sizes, int n_in,
                              void* d_out, int out_size, void* d_ws, size_t ws_size,
                              hipStream_t stream) {
  const float* x     = (const float*)d_in[0];
  const float* Wq    = (const float*)d_in[1];
  const float* Wk    = (const float*)d_in[2];
  const float* Wv    = (const float*)d_in[3];
  const float* Wp    = (const float*)d_in[4];
  const float* gamma = (const float*)d_in[5];
  const float* beta  = (const float*)d_in[6];
  const float* mean  = (const float*)d_in[7];
  const float* var   = (const float*)d_in[8];
  float* out = (float*)d_out;

  char* wsp = (char*)d_ws;
  unsigned short* qhp = (unsigned short*)wsp; wsp += (size_t)BD * ND * DA * 2;
  unsigned short* khp = (unsigned short*)wsp; wsp += (size_t)BD * ND * DA * 2;
  unsigned short* klp = (unsigned short*)wsp; wsp += (size_t)BD * ND * DA * 2;
  unsigned short* vT  = (unsigned short*)wsp; wsp += (size_t)BD * CD * ND * 2;
  unsigned short* xTh = (unsigned short*)wsp; wsp += (size_t)BD * ND * CD * 2;  // aliased as y
  unsigned short* xTl = (unsigned short*)wsp; wsp += (size_t)BD * ND * CD * 2;
  unsigned short* Wch = (unsigned short*)wsp; wsp += (size_t)384 * 256 * 2;
  unsigned short* Wcl = (unsigned short*)wsp; wsp += (size_t)384 * 256 * 2;
  unsigned short* Wph = (unsigned short*)wsp; wsp += (size_t)256 * 256 * 2;
  unsigned short* Wpl = (unsigned short*)wsp; wsp += (size_t)256 * 256 * 2;
  float* Drec = (float*)wsp; wsp += (size_t)BD * ND * 4;
  float* Dp   = (float*)wsp; wsp += (size_t)2 * BD * ND * 4;
  float* Rs   = (float*)wsp; wsp += (size_t)2 * BD * ND * 4;
  float* Oa   = (float*)wsp; wsp += (size_t)2 * BD * ND * CD * 4;  // 67.1 MB
  unsigned short* y = xTh;  // xTh consumed+overwritten by k_comb

  dim3 blk(256), blk5(512);
  k_prep<<<dim3(ND / 64, CD / 64, BD), blk, 0, stream>>>(x, xTh, xTl);
  k_prepW<<<dim3(160), blk, 0, stream>>>(Wq, Wk, Wv, Wp, Wch, Wcl, Wph, Wpl);
  k_proj<<<dim3(ND / 128, BD), blk5, 0, stream>>>(xTh, xTl, Wch, Wcl, qhp, khp,
                                                  klp, vT);
  k_colsum<<<dim3(512), blk5, 0, stream>>>(qhp, khp, klp, Dp);
  k_rcp<<<dim3(32), blk, 0, stream>>>(Dp, Drec);
  k_attn<<<dim3(512), blk5, 0, stream>>>(qhp, khp, klp, vT, Drec, Oa, Rs);
  k_comb<<<dim3(8192), blk, 0, stream>>>(Oa, Rs, y, xTl);
  k_final<<<dim3(2048), blk, 0, stream>>>(y, Wph, x, gamma, beta, mean, var, out);
}

// Round 11
// 469.133 us; speedup vs baseline: 1.6942x; 1.6942x over previous
//
#include <hip/hip_runtime.h>
#include <math.h>

#define BD 8
#define CD 256
#define ND 4096
#define DA 64

typedef __attribute__((ext_vector_type(8))) short short8v;
typedef __attribute__((ext_vector_type(4))) float float4v;

static __device__ __forceinline__ float4v mfma16(short8v a, short8v b, float4v c) {
  return __builtin_amdgcn_mfma_f32_16x16x32_bf16(a, b, c, 0, 0, 0);
}
static __device__ __forceinline__ unsigned short f2bf(float f) {
  union { float f; unsigned int u; } v; v.f = f;
  return (unsigned short)((v.u + 0x7fffu + ((v.u >> 16) & 1u)) >> 16);
}
static __device__ __forceinline__ float bf2f(unsigned short h) {
  union { unsigned int u; float f; } v; v.u = (unsigned int)h << 16;
  return v.f;
}
// XOR-swizzled LDS offset (ushort units) for rows of 64 bf16 (8 x 16B chunks).
static __device__ __forceinline__ int sw(int row, int c8) {
  return row * 64 + (((c8) ^ (row & 7)) << 3);
}
typedef const __attribute__((address_space(1))) unsigned int g_u32;
typedef __attribute__((address_space(3))) unsigned int l_u32;
static __device__ __forceinline__ void gld16(const void* g, void* l) {
  __builtin_amdgcn_global_load_lds((g_u32*)g, (l_u32*)l, 16, 0, 0);
}

// ---------------------------------------------------------------------------
// k_prep: x [b][c][n] fp32 -> xTh/xTl [b][n][256] split bf16 (transposed).
// ---------------------------------------------------------------------------
__global__ __launch_bounds__(256) void k_prep(const float* __restrict__ x,
                                              unsigned short* __restrict__ xTh,
                                              unsigned short* __restrict__ xTl) {
  const int n0 = blockIdx.x * 64, c0 = blockIdx.y * 64, b = blockIdx.z;
  __shared__ float Xs[64][68];
  const int tid = threadIdx.x;
  const int r0 = tid >> 4, col4 = (tid & 15) * 4;
#pragma unroll
  for (int j = 0; j < 4; ++j) {
    int r = r0 + j * 16;
    *(float4*)&Xs[r][col4] =
        *(const float4*)&x[((size_t)(b * CD + c0 + r)) * ND + n0 + col4];
  }
  __syncthreads();
  const int n = tid >> 2, cg = (tid & 3) * 16;
  unsigned short h[16], l[16];
#pragma unroll
  for (int j = 0; j < 16; ++j) {
    float v = Xs[cg + j][n];
    h[j] = f2bf(v);
    l[j] = f2bf(v - bf2f(h[j]));
  }
  size_t o = ((size_t)b * ND + n0 + n) * CD + c0 + cg;
#pragma unroll
  for (int j = 0; j < 4; ++j) {
    *(ushort4*)&xTh[o + j * 4] = *(ushort4*)&h[j * 4];
    *(ushort4*)&xTl[o + j * 4] = *(ushort4*)&l[j * 4];
  }
}

// ---------------------------------------------------------------------------
// k_prepW: split weights fp32 -> bf16 hi/lo. Wch/Wcl = [Wq;Wk;Wv] rows 0..383.
// ---------------------------------------------------------------------------
__global__ void k_prepW(const float* __restrict__ Wq, const float* __restrict__ Wk,
                        const float* __restrict__ Wv, const float* __restrict__ Wp,
                        unsigned short* Wch, unsigned short* Wcl,
                        unsigned short* Wph, unsigned short* Wpl) {
  int i = blockIdx.x * 256 + threadIdx.x;  // 640 rows x 64 float4
  int row = i >> 6, c4 = (i & 63) * 4;
  const float* src; unsigned short *dh, *dl; int r, drow;
  if (row < 64)       { src = Wq; r = row;       dh = Wch; dl = Wcl; drow = row; }
  else if (row < 128) { src = Wk; r = row - 64;  dh = Wch; dl = Wcl; drow = row; }
  else if (row < 384) { src = Wv; r = row - 128; dh = Wch; dl = Wcl; drow = row; }
  else                { src = Wp; r = row - 384; dh = Wph; dl = Wpl; drow = row - 384; }
  float4 f = *(const float4*)&src[(size_t)r * 256 + c4];
  ushort4 hh, ll;
  hh.x = f2bf(f.x); hh.y = f2bf(f.y); hh.z = f2bf(f.z); hh.w = f2bf(f.w);
  ll.x = f2bf(f.x - bf2f(hh.x)); ll.y = f2bf(f.y - bf2f(hh.y));
  ll.z = f2bf(f.z - bf2f(hh.z)); ll.w = f2bf(f.w - bf2f(hh.w));
  *(ushort4*)&dh[(size_t)drow * 256 + c4] = hh;
  *(ushort4*)&dl[(size_t)drow * 256 + c4] = ll;
}

// ---------------------------------------------------------------------------
// k_proj: MERGED q/k/v projection (reads xT once, LDS k-slices, 3-product).
// grid (ND/128, B), 512 thr. q: hi only; k: hi+lo; v: transposed bf16.
// ---------------------------------------------------------------------------
__global__ __launch_bounds__(512) void k_proj(
    const unsigned short* __restrict__ xTh, const unsigned short* __restrict__ xTl,
    const unsigned short* __restrict__ Wch, const unsigned short* __restrict__ Wcl,
    unsigned short* __restrict__ qh, unsigned short* __restrict__ kh,
    unsigned short* __restrict__ kl, unsigned short* __restrict__ vT) {
  const int n0 = blockIdx.x * 128, b = blockIdx.y;
  const int tid = threadIdx.x, w = tid >> 6, lane = tid & 63, lq = lane & 15,
            quad = lane >> 4;
  __shared__ __align__(16) unsigned short xs[2][2][128][40];
  float4v O[24];
#pragma unroll
  for (int t = 0; t < 24; ++t) O[t] = (float4v){0.f, 0.f, 0.f, 0.f};

  const int srow = tid >> 2, sc4 = tid & 3;
  uint4 rh, rl;
  auto load_slice = [&](int ks) {
    size_t a = ((size_t)b * ND + n0 + srow) * CD + ks * 32 + sc4 * 8;
    rh = *(const uint4*)(xTh + a);
    rl = *(const uint4*)(xTl + a);
  };
  auto write_slice = [&](int buf) {
    *(uint4*)&xs[buf][0][srow][sc4 * 8] = rh;
    *(uint4*)&xs[buf][1][srow][sc4 * 8] = rl;
  };
  load_slice(0); write_slice(0);
#pragma unroll 1
  for (int ks = 0; ks < 8; ++ks) {
    __syncthreads();
    if (ks < 7) load_slice(ks + 1);
    short8v bxh = *(const short8v*)&xs[ks & 1][0][w * 16 + lq][quad * 8];
    short8v bxl = *(const short8v*)&xs[ks & 1][1][w * 16 + lq][quad * 8];
#pragma unroll
    for (int t = 0; t < 24; ++t) {
      size_t a = (size_t)(t * 16 + lq) * CD + ks * 32 + quad * 8;
      short8v awh = *(const short8v*)(Wch + a);
      short8v awl = *(const short8v*)(Wcl + a);
      O[t] = mfma16(awh, bxh, O[t]);
      O[t] = mfma16(awl, bxh, O[t]);
      O[t] = mfma16(awh, bxl, O[t]);
    }
    if (ks < 7) write_slice((ks + 1) & 1);
  }
  const int n = n0 + w * 16 + lq;
#pragma unroll
  for (int t = 0; t < 24; ++t) {
    if (t < 4) {
      ushort4 hh;
      hh.x = f2bf(O[t][0]); hh.y = f2bf(O[t][1]);
      hh.z = f2bf(O[t][2]); hh.w = f2bf(O[t][3]);
      *(ushort4*)&qh[((size_t)b * ND + n) * DA + t * 16 + quad * 4] = hh;
    } else if (t < 8) {
      ushort4 hh, ll;
      hh.x = f2bf(O[t][0]); hh.y = f2bf(O[t][1]);
      hh.z = f2bf(O[t][2]); hh.w = f2bf(O[t][3]);
      ll.x = f2bf(O[t][0] - bf2f(hh.x)); ll.y = f2bf(O[t][1] - bf2f(hh.y));
      ll.z = f2bf(O[t][2] - bf2f(hh.z)); ll.w = f2bf(O[t][3] - bf2f(hh.w));
      size_t o = ((size_t)b * ND + n) * DA + (t - 4) * 16 + quad * 4;
      *(ushort4*)&kh[o] = hh;
      *(ushort4*)&kl[o] = ll;
    } else {
#pragma unroll
      for (int r = 0; r < 4; ++r) {
        int c = (t - 8) * 16 + quad * 4 + r;
        vT[((size_t)b * CD + c) * ND + n] = f2bf(O[t][r]);
      }
    }
  }
}

// ---------------------------------------------------------------------------
// k_colsum v2 (R9): column sums of exp(e), depth-2 MFMA/exp pipeline.
// ---------------------------------------------------------------------------
__global__ __launch_bounds__(512, 4) void k_colsum(
    const unsigned short* __restrict__ qh, const unsigned short* __restrict__ khp,
    const unsigned short* __restrict__ klp, float* __restrict__ Dp) {
  const int bid = blockIdx.x, b = bid & 7, half = (bid >> 3) & 1,
            m0 = (bid >> 4) * 128;
  const int nbase = half * 2048;
  const int tid = threadIdx.x, w = tid >> 6, lane = tid & 63, lq = lane & 15,
            quad = lane >> 4;
  const int mq = w & 3, nh = w >> 2;
  __shared__ __align__(16) unsigned short qbuf[3][4096];  // 64n x 64d swizzled
  __shared__ float Cb[128];
  short8v bkh[2][2], bkl[2][2];
#pragma unroll
  for (int sub = 0; sub < 2; ++sub)
#pragma unroll
    for (int k = 0; k < 2; ++k) {
      size_t a = ((size_t)b * ND + m0 + mq * 32 + sub * 16 + lq) * DA + k * 32 + quad * 8;
      bkh[sub][k] = *(const short8v*)(khp + a);
      bkl[sub][k] = *(const short8v*)(klp + a);
    }
  const int srow = w * 8 + (lane >> 3), sck = lane & 7;
  auto stageQ = [&](int it, int qn) {
    const unsigned short* src = qh + ((size_t)b * ND + nbase + it * 64 + srow) * DA +
                                ((sck ^ (srow & 7)) << 3);
    gld16(src, &qbuf[qn][0] + (size_t)w * 512);
  };
  stageQ(0, 0);
  stageQ(1, 1);
  asm volatile("s_waitcnt vmcnt(1)\n\ts_barrier" ::: "memory");
  float cs0 = 0.f, cs1 = 0.f;
  float4v accP[2][2];
  int rc = 0, sc = 2;
#pragma unroll 1
  for (int i = 0; i < 32; ++i) {
    if (i < 30) { stageQ(i + 2, sc); sc = (sc + 1 == 3) ? 0 : sc + 1; }
    float4v accN[2][2];
#pragma unroll
    for (int s = 0; s < 2; ++s) {
      short8v ah[2];
#pragma unroll
      for (int k = 0; k < 2; ++k)
        ah[k] = *(const short8v*)&qbuf[rc][sw(nh * 32 + s * 16 + lq, k * 4 + quad)];
#pragma unroll
      for (int sub = 0; sub < 2; ++sub) {
        float4v acc = {0.f, 0.f, 0.f, 0.f};
#pragma unroll
        for (int k = 0; k < 2; ++k) {
          acc = mfma16(ah[k], bkh[sub][k], acc);
          acc = mfma16(ah[k], bkl[sub][k], acc);
        }
        accN[s][sub] = acc;
      }
    }
    if (i > 0) {
#pragma unroll
      for (int s = 0; s < 2; ++s)
#pragma unroll
        for (int sub = 0; sub < 2; ++sub) {
          float e0 = __expf(accP[s][sub][0]) + __expf(accP[s][sub][1]) +
                     __expf(accP[s][sub][2]) + __expf(accP[s][sub][3]);
          if (sub == 0) cs0 += e0; else cs1 += e0;
        }
    }
#pragma unroll
    for (int s = 0; s < 2; ++s)
#pragma unroll
      for (int sub = 0; sub < 2; ++sub) accP[s][sub] = accN[s][sub];
    rc = (rc + 1 == 3) ? 0 : rc + 1;
    if (i < 30)
      asm volatile("s_waitcnt vmcnt(1) lgkmcnt(0)\n\ts_barrier" ::: "memory");
    else
      asm volatile("s_waitcnt vmcnt(0) lgkmcnt(0)\n\ts_barrier" ::: "memory");
  }
#pragma unroll
  for (int s = 0; s < 2; ++s)
#pragma unroll
    for (int sub = 0; sub < 2; ++sub) {
      float e0 = __expf(accP[s][sub][0]) + __expf(accP[s][sub][1]) +
                 __expf(accP[s][sub][2]) + __expf(accP[s][sub][3]);
      if (sub == 0) cs0 += e0; else cs1 += e0;
    }
  cs0 += __shfl_down(cs0, 16); cs0 += __shfl_down(cs0, 32);
  cs1 += __shfl_down(cs1, 16); cs1 += __shfl_down(cs1, 32);
  if (nh == 0 && lane < 16) {
    Cb[mq * 32 + lane] = cs0;
    Cb[mq * 32 + 16 + lane] = cs1;
  }
  __syncthreads();
  if (nh == 1 && lane < 16) {
    float t0 = Cb[mq * 32 + lane] + cs0;
    float t1 = Cb[mq * 32 + 16 + lane] + cs1;
    size_t o = (size_t)half * (BD * ND) + (size_t)b * ND + m0 + mq * 32 + lane;
    Dp[o] = t0;
    Dp[o + 16] = t1;
  }
}

// combine halves: Drec = 1/(Dp0+Dp1). grid 32 x 256.
__global__ void k_rcp(const float* __restrict__ Dp, float* __restrict__ Drec) {
  int i = blockIdx.x * 256 + threadIdx.x;
  float4 a = *(const float4*)&Dp[(size_t)i * 4];
  float4 c = *(const float4*)&Dp[(size_t)(BD * ND) + (size_t)i * 4];
  float4 r;
  r.x = 1.f / (a.x + c.x); r.y = 1.f / (a.y + c.y);
  r.z = 1.f / (a.z + c.z); r.w = 1.f / (a.w + c.w);
  *(float4*)&Drec[(size_t)i * 4] = r;
}

// ---------------------------------------------------------------------------
// k_attn v11 = v10 with the ONE-LINE FIX: __launch_bounds__(512, 2).
// R10's (512,4) capped the allocator below the ~100-VGPR working set ->
// VGPR_Count=64 + O/frags spilled to scratch (1.2GB fetch / 0.9GB write of
// spill traffic). Residency is set by LDS anyway: 81920B x 2 = exactly
// 160KiB -> 2 blocks/CU; 16 waves x ~100 VGPR = 1600 < 2048 regfile.
// Structure unchanged from R10 (m-split 2 blocks/CU, R9 wave shape +
// depth-2 exp pipeline, O/rs fp32 partials, k_comb epilogue).
// ---------------------------------------------------------------------------
__global__ __launch_bounds__(512, 2) void k_attn(
    const unsigned short* __restrict__ qh, const unsigned short* __restrict__ khp,
    const unsigned short* __restrict__ klp, const unsigned short* __restrict__ vT,
    const float* __restrict__ Drec, float* __restrict__ Oa,
    float* __restrict__ Rs) {
  const int bid = blockIdx.x, b = bid & 7, nt = (bid >> 3) & 31, mhalf = bid >> 8;
  const int n0 = nt * 128, mbase = mhalf * 32;  // m-tile base (tiles of 64)
  const int tid = threadIdx.x, w = tid >> 6, lane = tid & 63, lq = lane & 15,
            quad = lane >> 4;
  const int nh = w & 1, mt = w >> 1;  // 2 n-halves x 4 m/c-quarters
  __shared__ __align__(16) unsigned char ldsraw[81920];
  unsigned short* vbuf = (unsigned short*)ldsraw;            // [2][16384] 256c x 64m swz
  unsigned short* Pb = (unsigned short*)(ldsraw + 65536);    // [8192] 128n x 64m swz

  // q B-frags (hi only), resident: wave's 64-n half
  short8v aq[4][2];
#pragma unroll
  for (int s = 0; s < 4; ++s)
#pragma unroll
    for (int k = 0; k < 2; ++k)
      aq[s][k] = *(const short8v*)(qh + ((size_t)b * ND + n0 + nh * 64 + s * 16 + lq) * DA +
                                   k * 32 + quad * 8);
  float4v O[4][4];  // [ct][s]
#pragma unroll
  for (int ct = 0; ct < 4; ++ct)
#pragma unroll
    for (int s = 0; s < 4; ++s) O[ct][s] = (float4v){0.f, 0.f, 0.f, 0.f};
  float rs[4] = {0.f, 0.f, 0.f, 0.f};

  // async vT staging: 2048 chunks, 4/thread, swizzle baked into source
  auto stageV = [&](int it, int vn) {
    unsigned short* base = vbuf + (size_t)vn * 16384;
#pragma unroll
    for (int j = 0; j < 4; ++j) {
      int cidx = tid + j * 512;
      int row = cidx >> 3, ckpos = cidx & 7;
      const unsigned short* src =
          vT + ((size_t)b * CD + row) * ND + (mbase + it) * 64 + ((ckpos ^ (row & 7)) << 3);
      gld16(src, base + (size_t)(w * 64 + j * 512) * 8);
    }
  };
  short8v kc[4];  // [k*2 + (h|l)]; wave's 16 K-rows = m-quarter mt (in-place)
  auto kload = [&](int it) {
#pragma unroll
    for (int k = 0; k < 2; ++k) {
      size_t a = ((size_t)b * ND + (mbase + it) * 64 + mt * 16 + lq) * DA + k * 32 + quad * 8;
      kc[k * 2 + 0] = *(const short8v*)(khp + a);
      kc[k * 2 + 1] = *(const short8v*)(klp + a);
    }
  };
  auto doPV = [&](const unsigned short* vc) {
#pragma unroll
    for (int ks = 0; ks < 2; ++ks) {
      short8v ap[4];
#pragma unroll
      for (int s = 0; s < 4; ++s)
        ap[s] = *(const short8v*)&Pb[sw(nh * 64 + s * 16 + lq, ks * 4 + quad)];
#pragma unroll
      for (int ct = 0; ct < 4; ++ct) {
        const int trow = (mt * 4 + ct) * 16 + lq;
        short8v bv = *(const short8v*)&vc[sw(trow, ks * 4 + quad)];
#pragma unroll
        for (int s = 0; s < 4; ++s) O[ct][s] = mfma16(bv, ap[s], O[ct][s]);
      }
    }
  };
  auto eMFMA = [&](float4v* dst) {
#pragma unroll
    for (int s = 0; s < 4; ++s) {
      float4v acc = {0.f, 0.f, 0.f, 0.f};
#pragma unroll
      for (int k = 0; k < 2; ++k) {
        acc = mfma16(kc[k * 2 + 0], aq[s][k], acc);
        acc = mfma16(kc[k * 2 + 1], aq[s][k], acc);
      }
      dst[s] = acc;
    }
  };

  float4 drc4, drn4;
  stageV(0, 0);
  kload(0);
  drc4 = *(const float4*)&Drec[(size_t)b * ND + (mbase + 0) * 64 + mt * 16 + quad * 4];
  float4v accP[4];
  eMFMA(accP);  // E(0); compiler waits on kc loads

#pragma unroll 1
  for (int i = 0; i < 32; ++i) {
    if (i < 31) {
      kload(i + 1);  // in-place: kc's last read was eMFMA at end of prev body
      drn4 = *(const float4*)&Drec[(size_t)b * ND + (mbase + i + 1) * 64 + mt * 16 + quad * 4];
      stageV(i + 1, (i + 1) & 1);
    }
    // ---- expPack(i): accP ready at body start; overlaps eMFMA below ----
#pragma unroll
    for (int s = 0; s < 4; ++s) {
      float p0 = __expf(accP[s][0]) * drc4.x;
      float p1 = __expf(accP[s][1]) * drc4.y;
      float p2 = __expf(accP[s][2]) * drc4.z;
      float p3 = __expf(accP[s][3]) * drc4.w;
      rs[s] += (p0 + p1) + (p2 + p3);
      unsigned int w0 =
          (__float_as_uint(p0) >> 16) | (__float_as_uint(p1) & 0xffff0000u);
      unsigned int w1 =
          (__float_as_uint(p2) >> 16) | (__float_as_uint(p3) & 0xffff0000u);
      const int nl = nh * 64 + s * 16 + lq;
      const int c8 = mt * 2 + (quad >> 1);
      uint2 wv; wv.x = w0; wv.y = w1;
      *(uint2*)&Pb[nl * 64 + ((c8 ^ (nl & 7)) << 3) + ((quad & 1) << 2)] = wv;
    }
    if (i < 31) {
      eMFMA(accP);  // E(i+1) from the kc loaded this body
      drc4 = drn4;
    }
    // barA: Pb(i) visible; stage(i) retired (older); stage(i+1) in flight
    if (i < 31)
      asm volatile("s_waitcnt vmcnt(4) lgkmcnt(0)\n\ts_barrier" ::: "memory");
    else
      asm volatile("s_waitcnt vmcnt(0) lgkmcnt(0)\n\ts_barrier" ::: "memory");
    doPV(vbuf + (size_t)(i & 1) * 16384);
    // barB: PV's LDS reads done before next expPack rewrites Pb / next
    // body's stage(i+2) DMA rewrites vbuf[i&1]
    if (i < 31)
      asm volatile("s_waitcnt lgkmcnt(0)\n\ts_barrier" ::: "memory");
  }

  // ---- rs partial: butterfly over quad, 4-way mt combine in LDS ----
#pragma unroll
  for (int s = 0; s < 4; ++s) {
    rs[s] += __shfl_xor(rs[s], 16);
    rs[s] += __shfl_xor(rs[s], 32);
  }
  __syncthreads();  // PV(31) reads of Pb done -> safe to alias Sb onto Pb
  float* Sb = (float*)Pb;  // [4][128]
  if (lane < 16) {
#pragma unroll
    for (int s = 0; s < 4; ++s) Sb[mt * 128 + nh * 64 + s * 16 + lane] = rs[s];
  }
  __syncthreads();
  if (mt == 0 && lane < 16) {
#pragma unroll
    for (int s = 0; s < 4; ++s) {
      const int nl = nh * 64 + s * 16 + lane;
      float tot = Sb[nl] + Sb[128 + nl] + Sb[256 + nl] + Sb[384 + nl];
      Rs[((size_t)mhalf * BD + b) * ND + n0 + nl] = tot;
    }
  }
  // ---- O partial write (fp32), combined in k_comb ----
#pragma unroll
  for (int ct = 0; ct < 4; ++ct) {
#pragma unroll
    for (int s = 0; s < 4; ++s) {
      const int n = n0 + nh * 64 + s * 16 + lq;
      const int c = (mt * 4 + ct) * 16 + quad * 4;
      float4 v;
      v.x = O[ct][s][0]; v.y = O[ct][s][1]; v.z = O[ct][s][2]; v.w = O[ct][s][3];
      *(float4*)&Oa[(((size_t)mhalf * BD + b) * ND + n) * CD + c] = v;
    }
  }
}

// ---------------------------------------------------------------------------
// k_comb: y = x - (O0+O1)/(rs0+rs1), in place over xhy. Memory-bound.
// grid 8192 x 256 (one thread = 4 consecutive c of one (b,n)).
// ---------------------------------------------------------------------------
__global__ __launch_bounds__(256) void k_comb(const float* __restrict__ Oa,
                                              const float* __restrict__ Rs,
                                              unsigned short* __restrict__ xhy,
                                              const unsigned short* __restrict__ xTl) {
  const int idx = blockIdx.x * 256 + threadIdx.x;  // 8*4096*64
  const int c4 = (idx & 63) * 4;
  const int n = (idx >> 6) & (ND - 1);
  const int b = idx >> 18;
  const size_t bn = (size_t)b * ND + n;
  float4 a = *(const float4*)&Oa[bn * CD + c4];
  float4 c = *(const float4*)&Oa[((size_t)BD * ND + bn) * CD + c4];
  const float rsc = 1.0f / (1e-9f + Rs[bn] + Rs[(size_t)BD * ND + bn]);
  const size_t off = bn * CD + c4;
  ushort4 h4 = *(const ushort4*)&xhy[off];
  ushort4 l4 = *(const ushort4*)&xTl[off];
  ushort4 o4;
  o4.x = f2bf(bf2f(h4.x) + bf2f(l4.x) - (a.x + c.x) * rsc);
  o4.y = f2bf(bf2f(h4.y) + bf2f(l4.y) - (a.y + c.y) * rsc);
  o4.z = f2bf(bf2f(h4.z) + bf2f(l4.z) - (a.z + c.z) * rsc);
  o4.w = f2bf(bf2f(h4.w) + bf2f(l4.w) - (a.w + c.w) * rsc);
  *(ushort4*)&xhy[off] = o4;
}

// ---------------------------------------------------------------------------
// k_final: h = Wp . y (bf16 MFMA); out = relu(BN(h)) + x.
// ---------------------------------------------------------------------------
__global__ __launch_bounds__(256) void k_final(const unsigned short* __restrict__ y,
                                               const unsigned short* __restrict__ Wpb,
                                               const float* __restrict__ x,
                                               const float* __restrict__ gamma,
                                               const float* __restrict__ beta,
                                               const float* __restrict__ mean,
                                               const float* __restrict__ var,
                                               float* __restrict__ out) {
  const int bid = blockIdx.x;
  const int b = bid & 7;
  const int rem = bid >> 3;
  const int n0 = (rem & 63) * 64;
  const int d0 = (rem >> 6) * 64;
  const int tid = threadIdx.x;
  const int wave = tid >> 6, lane = tid & 63, lq = lane & 15, quad = lane >> 4;
  const int dw = d0 + wave * 16;
  float4v O[4];
#pragma unroll
  for (int s = 0; s < 4; ++s) O[s] = (float4v){0.f, 0.f, 0.f, 0.f};
#pragma unroll
  for (int chh = 0; chh < 8; ++chh) {
    const size_t ab = (size_t)(dw + lq) * CD + chh * 32 + quad * 8;
    short8v a0 = *(const short8v*)(Wpb + ab);
#pragma unroll
    for (int s = 0; s < 4; ++s) {
      const size_t bb = ((size_t)b * ND + n0 + s * 16 + lq) * CD + chh * 32 + quad * 8;
      short8v bv = *(const short8v*)(y + bb);
      O[s] = mfma16(a0, bv, O[s]);
    }
  }
#pragma unroll
  for (int r = 0; r < 4; ++r) {
    const int d = dw + quad * 4 + r;
    const float inv  = gamma[d] / sqrtf(var[d] + 1e-5f);
    const float bias = beta[d] - mean[d] * inv;
#pragma unroll
    for (int s = 0; s < 4; ++s) {
      const int n = n0 + s * 16 + lq;
      const size_t oi = ((size_t)b * CD + d) * ND + n;
      out[oi] = fmaxf(O[s][r] * inv + bias, 0.f) + x[oi];
    }
  }
}

extern "C" void kernel_launch(void* const* d_in, const int* in_sizes, int n_in,
                              void* d_out, int out_size, void* d_ws, size_t ws_size,
                              hipStream_t stream) {
  const float* x     = (const float*)d_in[0];
  const float* Wq    = (const float*)d_in[1];
  const float* Wk    = (const float*)d_in[2];
  const float* Wv    = (const float*)d_in[3];
  const float* Wp    = (const float*)d_in[4];
  const float* gamma = (const float*)d_in[5];
  const float* beta  = (const float*)d_in[6];
  const float* mean  = (const float*)d_in[7];
  const float* var   = (const float*)d_in[8];
  float* out = (float*)d_out;

  char* wsp = (char*)d_ws;
  unsigned short* qhp = (unsigned short*)wsp; wsp += (size_t)BD * ND * DA * 2;
  unsigned short* khp = (unsigned short*)wsp; wsp += (size_t)BD * ND * DA * 2;
  unsigned short* klp = (unsigned short*)wsp; wsp += (size_t)BD * ND * DA * 2;
  unsigned short* vT  = (unsigned short*)wsp; wsp += (size_t)BD * CD * ND * 2;
  unsigned short* xTh = (unsigned short*)wsp; wsp += (size_t)BD * ND * CD * 2;  // aliased as y
  unsigned short* xTl = (unsigned short*)wsp; wsp += (size_t)BD * ND * CD * 2;
  unsigned short* Wch = (unsigned short*)wsp; wsp += (size_t)384 * 256 * 2;
  unsigned short* Wcl = (unsigned short*)wsp; wsp += (size_t)384 * 256 * 2;
  unsigned short* Wph = (unsigned short*)wsp; wsp += (size_t)256 * 256 * 2;
  unsigned short* Wpl = (unsigned short*)wsp; wsp += (size_t)256 * 256 * 2;
  float* Drec = (float*)wsp; wsp += (size_t)BD * ND * 4;
  float* Dp   = (float*)wsp; wsp += (size_t)2 * BD * ND * 4;
  float* Rs   = (float*)wsp; wsp += (size_t)2 * BD * ND * 4;
  float* Oa   = (float*)wsp; wsp += (size_t)2 * BD * ND * CD * 4;  // 67.1 MB
  unsigned short* y = xTh;  // xTh consumed+overwritten by k_comb

  dim3 blk(256), blk5(512);
  k_prep<<<dim3(ND / 64, CD / 64, BD), blk, 0, stream>>>(x, xTh, xTl);
  k_prepW<<<dim3(160), blk, 0, stream>>>(Wq, Wk, Wv, Wp, Wch, Wcl, Wph, Wpl);
  k_proj<<<dim3(ND / 128, BD), blk5, 0, stream>>>(xTh, xTl, Wch, Wcl, qhp, khp,
                                                  klp, vT);
  k_colsum<<<dim3(512), blk5, 0, stream>>>(qhp, khp, klp, Dp);
  k_rcp<<<dim3(32), blk, 0, stream>>>(Dp, Drec);
  k_attn<<<dim3(512), blk5, 0, stream>>>(qhp, khp, klp, vT, Drec, Oa, Rs);
  k_comb<<<dim3(8192), blk, 0, stream>>>(Oa, Rs, y, xTl);
  k_final<<<dim3(2048), blk, 0, stream>>>(y, Wph, x, gamma, beta, mean, var, out);
}

// Round 12
// 436.984 us; speedup vs baseline: 1.8189x; 1.0736x over previous
//
#include <hip/hip_runtime.h>
#include <math.h>

#define BD 8
#define CD 256
#define ND 4096
#define DA 64

typedef __attribute__((ext_vector_type(8))) short short8v;
typedef __attribute__((ext_vector_type(4))) float float4v;

static __device__ __forceinline__ float4v mfma16(short8v a, short8v b, float4v c) {
  return __builtin_amdgcn_mfma_f32_16x16x32_bf16(a, b, c, 0, 0, 0);
}
static __device__ __forceinline__ unsigned short f2bf(float f) {
  union { float f; unsigned int u; } v; v.f = f;
  return (unsigned short)((v.u + 0x7fffu + ((v.u >> 16) & 1u)) >> 16);
}
static __device__ __forceinline__ float bf2f(unsigned short h) {
  union { unsigned int u; float f; } v; v.u = (unsigned int)h << 16;
  return v.f;
}
// XOR-swizzled LDS offset (ushort units) for rows of 64 bf16 (8 x 16B chunks).
static __device__ __forceinline__ int sw(int row, int c8) {
  return row * 64 + (((c8) ^ (row & 7)) << 3);
}
typedef const __attribute__((address_space(1))) unsigned int g_u32;
typedef __attribute__((address_space(3))) unsigned int l_u32;
static __device__ __forceinline__ void gld16(const void* g, void* l) {
  __builtin_amdgcn_global_load_lds((g_u32*)g, (l_u32*)l, 16, 0, 0);
}

// ---------------------------------------------------------------------------
// k_prep: x [b][c][n] fp32 -> xTh/xTl [b][n][256] split bf16 (transposed).
// ---------------------------------------------------------------------------
__global__ __launch_bounds__(256) void k_prep(const float* __restrict__ x,
                                              unsigned short* __restrict__ xTh,
                                              unsigned short* __restrict__ xTl) {
  const int n0 = blockIdx.x * 64, c0 = blockIdx.y * 64, b = blockIdx.z;
  __shared__ float Xs[64][68];
  const int tid = threadIdx.x;
  const int r0 = tid >> 4, col4 = (tid & 15) * 4;
#pragma unroll
  for (int j = 0; j < 4; ++j) {
    int r = r0 + j * 16;
    *(float4*)&Xs[r][col4] =
        *(const float4*)&x[((size_t)(b * CD + c0 + r)) * ND + n0 + col4];
  }
  __syncthreads();
  const int n = tid >> 2, cg = (tid & 3) * 16;
  unsigned short h[16], l[16];
#pragma unroll
  for (int j = 0; j < 16; ++j) {
    float v = Xs[cg + j][n];
    h[j] = f2bf(v);
    l[j] = f2bf(v - bf2f(h[j]));
  }
  size_t o = ((size_t)b * ND + n0 + n) * CD + c0 + cg;
#pragma unroll
  for (int j = 0; j < 4; ++j) {
    *(ushort4*)&xTh[o + j * 4] = *(ushort4*)&h[j * 4];
    *(ushort4*)&xTl[o + j * 4] = *(ushort4*)&l[j * 4];
  }
}

// ---------------------------------------------------------------------------
// k_prepW: split weights fp32 -> bf16 hi/lo. Wch/Wcl = [Wq;Wk;Wv] rows 0..383.
// ---------------------------------------------------------------------------
__global__ void k_prepW(const float* __restrict__ Wq, const float* __restrict__ Wk,
                        const float* __restrict__ Wv, const float* __restrict__ Wp,
                        unsigned short* Wch, unsigned short* Wcl,
                        unsigned short* Wph, unsigned short* Wpl) {
  int i = blockIdx.x * 256 + threadIdx.x;  // 640 rows x 64 float4
  int row = i >> 6, c4 = (i & 63) * 4;
  const float* src; unsigned short *dh, *dl; int r, drow;
  if (row < 64)       { src = Wq; r = row;       dh = Wch; dl = Wcl; drow = row; }
  else if (row < 128) { src = Wk; r = row - 64;  dh = Wch; dl = Wcl; drow = row; }
  else if (row < 384) { src = Wv; r = row - 128; dh = Wch; dl = Wcl; drow = row; }
  else                { src = Wp; r = row - 384; dh = Wph; dl = Wpl; drow = row - 384; }
  float4 f = *(const float4*)&src[(size_t)r * 256 + c4];
  ushort4 hh, ll;
  hh.x = f2bf(f.x); hh.y = f2bf(f.y); hh.z = f2bf(f.z); hh.w = f2bf(f.w);
  ll.x = f2bf(f.x - bf2f(hh.x)); ll.y = f2bf(f.y - bf2f(hh.y));
  ll.z = f2bf(f.z - bf2f(hh.z)); ll.w = f2bf(f.w - bf2f(hh.w));
  *(ushort4*)&dh[(size_t)drow * 256 + c4] = hh;
  *(ushort4*)&dl[(size_t)drow * 256 + c4] = ll;
}

// ---------------------------------------------------------------------------
// k_proj: MERGED q/k/v projection (reads xT once, LDS k-slices, 3-product).
// grid (ND/128, B), 512 thr. q: hi only; k: hi+lo; v: transposed bf16.
// ---------------------------------------------------------------------------
__global__ __launch_bounds__(512) void k_proj(
    const unsigned short* __restrict__ xTh, const unsigned short* __restrict__ xTl,
    const unsigned short* __restrict__ Wch, const unsigned short* __restrict__ Wcl,
    unsigned short* __restrict__ qh, unsigned short* __restrict__ kh,
    unsigned short* __restrict__ kl, unsigned short* __restrict__ vT) {
  const int n0 = blockIdx.x * 128, b = blockIdx.y;
  const int tid = threadIdx.x, w = tid >> 6, lane = tid & 63, lq = lane & 15,
            quad = lane >> 4;
  __shared__ __align__(16) unsigned short xs[2][2][128][40];
  float4v O[24];
#pragma unroll
  for (int t = 0; t < 24; ++t) O[t] = (float4v){0.f, 0.f, 0.f, 0.f};

  const int srow = tid >> 2, sc4 = tid & 3;
  uint4 rh, rl;
  auto load_slice = [&](int ks) {
    size_t a = ((size_t)b * ND + n0 + srow) * CD + ks * 32 + sc4 * 8;
    rh = *(const uint4*)(xTh + a);
    rl = *(const uint4*)(xTl + a);
  };
  auto write_slice = [&](int buf) {
    *(uint4*)&xs[buf][0][srow][sc4 * 8] = rh;
    *(uint4*)&xs[buf][1][srow][sc4 * 8] = rl;
  };
  load_slice(0); write_slice(0);
#pragma unroll 1
  for (int ks = 0; ks < 8; ++ks) {
    __syncthreads();
    if (ks < 7) load_slice(ks + 1);
    short8v bxh = *(const short8v*)&xs[ks & 1][0][w * 16 + lq][quad * 8];
    short8v bxl = *(const short8v*)&xs[ks & 1][1][w * 16 + lq][quad * 8];
#pragma unroll
    for (int t = 0; t < 24; ++t) {
      size_t a = (size_t)(t * 16 + lq) * CD + ks * 32 + quad * 8;
      short8v awh = *(const short8v*)(Wch + a);
      short8v awl = *(const short8v*)(Wcl + a);
      O[t] = mfma16(awh, bxh, O[t]);
      O[t] = mfma16(awl, bxh, O[t]);
      O[t] = mfma16(awh, bxl, O[t]);
    }
    if (ks < 7) write_slice((ks + 1) & 1);
  }
  const int n = n0 + w * 16 + lq;
#pragma unroll
  for (int t = 0; t < 24; ++t) {
    if (t < 4) {
      ushort4 hh;
      hh.x = f2bf(O[t][0]); hh.y = f2bf(O[t][1]);
      hh.z = f2bf(O[t][2]); hh.w = f2bf(O[t][3]);
      *(ushort4*)&qh[((size_t)b * ND + n) * DA + t * 16 + quad * 4] = hh;
    } else if (t < 8) {
      ushort4 hh, ll;
      hh.x = f2bf(O[t][0]); hh.y = f2bf(O[t][1]);
      hh.z = f2bf(O[t][2]); hh.w = f2bf(O[t][3]);
      ll.x = f2bf(O[t][0] - bf2f(hh.x)); ll.y = f2bf(O[t][1] - bf2f(hh.y));
      ll.z = f2bf(O[t][2] - bf2f(hh.z)); ll.w = f2bf(O[t][3] - bf2f(hh.w));
      size_t o = ((size_t)b * ND + n) * DA + (t - 4) * 16 + quad * 4;
      *(ushort4*)&kh[o] = hh;
      *(ushort4*)&kl[o] = ll;
    } else {
#pragma unroll
      for (int r = 0; r < 4; ++r) {
        int c = (t - 8) * 16 + quad * 4 + r;
        vT[((size_t)b * CD + c) * ND + n] = f2bf(O[t][r]);
      }
    }
  }
}

// ---------------------------------------------------------------------------
// k_colsum (R9): column sums of exp(e), depth-2 MFMA/exp pipeline,
// + T5 s_setprio around the MFMA cluster.
// ---------------------------------------------------------------------------
__global__ __launch_bounds__(512, 4) void k_colsum(
    const unsigned short* __restrict__ qh, const unsigned short* __restrict__ khp,
    const unsigned short* __restrict__ klp, float* __restrict__ Dp) {
  const int bid = blockIdx.x, b = bid & 7, half = (bid >> 3) & 1,
            m0 = (bid >> 4) * 128;
  const int nbase = half * 2048;
  const int tid = threadIdx.x, w = tid >> 6, lane = tid & 63, lq = lane & 15,
            quad = lane >> 4;
  const int mq = w & 3, nh = w >> 2;
  __shared__ __align__(16) unsigned short qbuf[3][4096];  // 64n x 64d swizzled
  __shared__ float Cb[128];
  short8v bkh[2][2], bkl[2][2];
#pragma unroll
  for (int sub = 0; sub < 2; ++sub)
#pragma unroll
    for (int k = 0; k < 2; ++k) {
      size_t a = ((size_t)b * ND + m0 + mq * 32 + sub * 16 + lq) * DA + k * 32 + quad * 8;
      bkh[sub][k] = *(const short8v*)(khp + a);
      bkl[sub][k] = *(const short8v*)(klp + a);
    }
  const int srow = w * 8 + (lane >> 3), sck = lane & 7;
  auto stageQ = [&](int it, int qn) {
    const unsigned short* src = qh + ((size_t)b * ND + nbase + it * 64 + srow) * DA +
                                ((sck ^ (srow & 7)) << 3);
    gld16(src, &qbuf[qn][0] + (size_t)w * 512);
  };
  stageQ(0, 0);
  stageQ(1, 1);
  asm volatile("s_waitcnt vmcnt(1)\n\ts_barrier" ::: "memory");
  float cs0 = 0.f, cs1 = 0.f;
  float4v accP[2][2];
  int rc = 0, sc = 2;
#pragma unroll 1
  for (int i = 0; i < 32; ++i) {
    if (i < 30) { stageQ(i + 2, sc); sc = (sc + 1 == 3) ? 0 : sc + 1; }
    float4v accN[2][2];
    __builtin_amdgcn_s_setprio(1);
#pragma unroll
    for (int s = 0; s < 2; ++s) {
      short8v ah[2];
#pragma unroll
      for (int k = 0; k < 2; ++k)
        ah[k] = *(const short8v*)&qbuf[rc][sw(nh * 32 + s * 16 + lq, k * 4 + quad)];
#pragma unroll
      for (int sub = 0; sub < 2; ++sub) {
        float4v acc = {0.f, 0.f, 0.f, 0.f};
#pragma unroll
        for (int k = 0; k < 2; ++k) {
          acc = mfma16(ah[k], bkh[sub][k], acc);
          acc = mfma16(ah[k], bkl[sub][k], acc);
        }
        accN[s][sub] = acc;
      }
    }
    __builtin_amdgcn_s_setprio(0);
    if (i > 0) {
#pragma unroll
      for (int s = 0; s < 2; ++s)
#pragma unroll
        for (int sub = 0; sub < 2; ++sub) {
          float e0 = __expf(accP[s][sub][0]) + __expf(accP[s][sub][1]) +
                     __expf(accP[s][sub][2]) + __expf(accP[s][sub][3]);
          if (sub == 0) cs0 += e0; else cs1 += e0;
        }
    }
#pragma unroll
    for (int s = 0; s < 2; ++s)
#pragma unroll
      for (int sub = 0; sub < 2; ++sub) accP[s][sub] = accN[s][sub];
    rc = (rc + 1 == 3) ? 0 : rc + 1;
    if (i < 30)
      asm volatile("s_waitcnt vmcnt(1) lgkmcnt(0)\n\ts_barrier" ::: "memory");
    else
      asm volatile("s_waitcnt vmcnt(0) lgkmcnt(0)\n\ts_barrier" ::: "memory");
  }
#pragma unroll
  for (int s = 0; s < 2; ++s)
#pragma unroll
    for (int sub = 0; sub < 2; ++sub) {
      float e0 = __expf(accP[s][sub][0]) + __expf(accP[s][sub][1]) +
                 __expf(accP[s][sub][2]) + __expf(accP[s][sub][3]);
      if (sub == 0) cs0 += e0; else cs1 += e0;
    }
  cs0 += __shfl_down(cs0, 16); cs0 += __shfl_down(cs0, 32);
  cs1 += __shfl_down(cs1, 16); cs1 += __shfl_down(cs1, 32);
  if (nh == 0 && lane < 16) {
    Cb[mq * 32 + lane] = cs0;
    Cb[mq * 32 + 16 + lane] = cs1;
  }
  __syncthreads();
  if (nh == 1 && lane < 16) {
    float t0 = Cb[mq * 32 + lane] + cs0;
    float t1 = Cb[mq * 32 + 16 + lane] + cs1;
    size_t o = (size_t)half * (BD * ND) + (size_t)b * ND + m0 + mq * 32 + lane;
    Dp[o] = t0;
    Dp[o + 16] = t1;
  }
}

// combine halves: Drec = 1/(Dp0+Dp1). grid 32 x 256.
__global__ void k_rcp(const float* __restrict__ Dp, float* __restrict__ Drec) {
  int i = blockIdx.x * 256 + threadIdx.x;
  float4 a = *(const float4*)&Dp[(size_t)i * 4];
  float4 c = *(const float4*)&Dp[(size_t)(BD * ND) + (size_t)i * 4];
  float4 r;
  r.x = 1.f / (a.x + c.x); r.y = 1.f / (a.y + c.y);
  r.z = 1.f / (a.z + c.z); r.w = 1.f / (a.w + c.w);
  *(float4*)&Drec[(size_t)i * 4] = r;
}

// ---------------------------------------------------------------------------
// k_attn v12 = R9 (verified 168.5us: mt4 x nh2 waves, triple vbuf, dbuf Pb,
// counted vmcnt(4) barrier, depth-2 exp pipeline) + T5 s_setprio(1) around
// the two pure-MFMA clusters (doPV, eMFMA). Mechanism: R9's body gives waves
// role diversity between barriers (some in VMEM-issue/expPack, some in MFMA);
// setprio lets the CU scheduler favor the matrix-feeding wave (m191: +4-7%
// attn; null only in pure lockstep). Zero numerical change.
// ---------------------------------------------------------------------------
__global__ __launch_bounds__(512, 2) void k_attn(
    const unsigned short* __restrict__ qh, const unsigned short* __restrict__ khp,
    const unsigned short* __restrict__ klp, const unsigned short* __restrict__ vT,
    const float* __restrict__ Drec, unsigned short* xhy,
    const unsigned short* __restrict__ xTl) {
  const int bid = blockIdx.x, b = bid & 7, n0 = (bid >> 3) * 128;
  const int tid = threadIdx.x, w = tid >> 6, lane = tid & 63, lq = lane & 15,
            quad = lane >> 4;
  const int nh = w & 1, mt = w >> 1;  // 2 n-halves x 4 m/c-quarters
  __shared__ __align__(16) unsigned short vbuf[3][16384];  // 256c x 64m swizzled
  __shared__ __align__(16) unsigned short Pb[2][8192];     // 128n x 64m swizzled
  __shared__ float Sb4[4][128];

  // q B-frags (hi only), resident: wave's 64-n half
  short8v aq[4][2];
#pragma unroll
  for (int s = 0; s < 4; ++s)
#pragma unroll
    for (int k = 0; k < 2; ++k)
      aq[s][k] = *(const short8v*)(qh + ((size_t)b * ND + n0 + nh * 64 + s * 16 + lq) * DA +
                                   k * 32 + quad * 8);
  float4v O[4][4];  // [ct][s]
#pragma unroll
  for (int ct = 0; ct < 4; ++ct)
#pragma unroll
    for (int s = 0; s < 4; ++s) O[ct][s] = (float4v){0.f, 0.f, 0.f, 0.f};
  float rs[4] = {0.f, 0.f, 0.f, 0.f};

  // async vT staging: 2048 chunks, 4/thread, swizzle baked into source
  auto stageV = [&](int mtile, int vn) {
    unsigned short* base = &vbuf[vn][0];
#pragma unroll
    for (int j = 0; j < 4; ++j) {
      int cidx = tid + j * 512;
      int row = cidx >> 3, ckpos = cidx & 7;
      const unsigned short* src =
          vT + ((size_t)b * CD + row) * ND + mtile * 64 + ((ckpos ^ (row & 7)) << 3);
      gld16(src, base + (size_t)(w * 64 + j * 512) * 8);
    }
  };
  short8v kc[4];  // [k*2 + (h|l)]; wave's 16 K-rows = m-quarter mt (in-place)
  auto kload = [&](int mtile) {
#pragma unroll
    for (int k = 0; k < 2; ++k) {
      size_t a = ((size_t)b * ND + mtile * 64 + mt * 16 + lq) * DA + k * 32 + quad * 8;
      kc[k * 2 + 0] = *(const short8v*)(khp + a);
      kc[k * 2 + 1] = *(const short8v*)(klp + a);
    }
  };
  auto doPV = [&](const unsigned short* Pc, const unsigned short* vc) {
    __builtin_amdgcn_s_setprio(1);
#pragma unroll
    for (int ks = 0; ks < 2; ++ks) {
      short8v ap[4];
#pragma unroll
      for (int s = 0; s < 4; ++s)
        ap[s] = *(const short8v*)&Pc[sw(nh * 64 + s * 16 + lq, ks * 4 + quad)];
#pragma unroll
      for (int ct = 0; ct < 4; ++ct) {
        const int trow = (mt * 4 + ct) * 16 + lq;
        short8v bv = *(const short8v*)&vc[sw(trow, ks * 4 + quad)];
#pragma unroll
        for (int s = 0; s < 4; ++s) O[ct][s] = mfma16(bv, ap[s], O[ct][s]);
      }
    }
    __builtin_amdgcn_s_setprio(0);
  };
  auto eMFMA = [&](float4v* dst) {
    __builtin_amdgcn_s_setprio(1);
#pragma unroll
    for (int s = 0; s < 4; ++s) {
      float4v acc = {0.f, 0.f, 0.f, 0.f};
#pragma unroll
      for (int k = 0; k < 2; ++k) {
        acc = mfma16(kc[k * 2 + 0], aq[s][k], acc);
        acc = mfma16(kc[k * 2 + 1], aq[s][k], acc);
      }
      dst[s] = acc;
    }
    __builtin_amdgcn_s_setprio(0);
  };

  float4 drc4, drn4;
  stageV(0, 0);
  kload(0);
  drc4 = *(const float4*)&Drec[(size_t)b * ND + mt * 16 + quad * 4];
  // prologue: e-MFMA(0) (compiler waits on kc loads)
  float4v accP[4];
  eMFMA(accP);

  int vs = 1, vp = 0;
#pragma unroll 1
  for (int i = 0; i < 64; ++i) {
    if (i > 0) {
      doPV(&Pb[(i - 1) & 1][0], &vbuf[vp][0]);
      vp = (vp + 1 == 3) ? 0 : vp + 1;
    }
    if (i < 63) {
      kload(i + 1);  // in-place: kc's last read was eMFMA at end of prev body
      drn4 = *(const float4*)&Drec[(size_t)b * ND + (i + 1) * 64 + mt * 16 + quad * 4];
      stageV(i + 1, vs);
      vs = (vs + 1 == 3) ? 0 : vs + 1;
    }
    // ---- expPack(i): accP ready at body start -> overlaps PV's MFMAs ----
    unsigned short* Pcur = &Pb[i & 1][0];
#pragma unroll
    for (int s = 0; s < 4; ++s) {
      float p0 = __expf(accP[s][0]) * drc4.x;
      float p1 = __expf(accP[s][1]) * drc4.y;
      float p2 = __expf(accP[s][2]) * drc4.z;
      float p3 = __expf(accP[s][3]) * drc4.w;
      rs[s] += (p0 + p1) + (p2 + p3);
      unsigned int w0 =
          (__float_as_uint(p0) >> 16) | (__float_as_uint(p1) & 0xffff0000u);
      unsigned int w1 =
          (__float_as_uint(p2) >> 16) | (__float_as_uint(p3) & 0xffff0000u);
      const int nl = nh * 64 + s * 16 + lq;
      const int c8 = mt * 2 + (quad >> 1);
      uint2 wv; wv.x = w0; wv.y = w1;
      *(uint2*)&Pcur[nl * 64 + ((c8 ^ (nl & 7)) << 3) + ((quad & 1) << 2)] = wv;
    }
    if (i < 63) {
      eMFMA(accP);  // for iter i+1, from the kc loaded this body
      drc4 = drn4;
    }
    // counted barrier: keep THIS body's 4 stage chunks in flight (consumed
    // at body(i+2)); kc/drn consumed above -> retired; stage(i) older ->
    // retired. Exactly 4 outstanding at the barrier.
    if (i < 63)
      asm volatile("s_waitcnt vmcnt(4) lgkmcnt(0)\n\ts_barrier" ::: "memory");
    else
      asm volatile("s_waitcnt vmcnt(0) lgkmcnt(0)\n\ts_barrier" ::: "memory");
  }
  doPV(&Pb[1][0], &vbuf[vp][0]);  // PV(63); 63&1 == 1, 63%3 == 0

  // ---- S reduction: butterfly over quad, then 4-way mt combine in LDS ----
#pragma unroll
  for (int s = 0; s < 4; ++s) {
    rs[s] += __shfl_xor(rs[s], 16);
    rs[s] += __shfl_xor(rs[s], 32);
  }
  if (lane < 16) {
#pragma unroll
    for (int s = 0; s < 4; ++s) Sb4[mt][nh * 64 + s * 16 + lane] = rs[s];
  }
  __syncthreads();
  float rsc[4];
#pragma unroll
  for (int s = 0; s < 4; ++s) {
    const int nloc = nh * 64 + s * 16 + lq;
    rsc[s] = 1.0f / (1e-9f + Sb4[0][nloc] + Sb4[1][nloc] + Sb4[2][nloc] + Sb4[3][nloc]);
  }
  // ---- y = x - O/S, in place over xTh (lane: 4 consecutive c, fixed n) ----
#pragma unroll
  for (int ct = 0; ct < 4; ++ct) {
    const int cb = (mt * 4 + ct) * 16 + quad * 4;
#pragma unroll
    for (int s = 0; s < 4; ++s) {
      const int n = n0 + nh * 64 + s * 16 + lq;
      const size_t off = ((size_t)b * ND + n) * CD + cb;
      ushort4 h4 = *(const ushort4*)&xhy[off];
      ushort4 l4 = *(const ushort4*)&xTl[off];
      ushort4 o4;
      o4.x = f2bf(bf2f(h4.x) + bf2f(l4.x) - O[ct][s][0] * rsc[s]);
      o4.y = f2bf(bf2f(h4.y) + bf2f(l4.y) - O[ct][s][1] * rsc[s]);
      o4.z = f2bf(bf2f(h4.z) + bf2f(l4.z) - O[ct][s][2] * rsc[s]);
      o4.w = f2bf(bf2f(h4.w) + bf2f(l4.w) - O[ct][s][3] * rsc[s]);
      *(ushort4*)&xhy[off] = o4;
    }
  }
}

// ---------------------------------------------------------------------------
// k_final: h = Wp . y (bf16 MFMA); out = relu(BN(h)) + x.
// ---------------------------------------------------------------------------
__global__ __launch_bounds__(256) void k_final(const unsigned short* __restrict__ y,
                                               const unsigned short* __restrict__ Wpb,
                                               const float* __restrict__ x,
                                               const float* __restrict__ gamma,
                                               const float* __restrict__ beta,
                                               const float* __restrict__ mean,
                                               const float* __restrict__ var,
                                               float* __restrict__ out) {
  const int bid = blockIdx.x;
  const int b = bid & 7;
  const int rem = bid >> 3;
  const int n0 = (rem & 63) * 64;
  const int d0 = (rem >> 6) * 64;
  const int tid = threadIdx.x;
  const int wave = tid >> 6, lane = tid & 63, lq = lane & 15, quad = lane >> 4;
  const int dw = d0 + wave * 16;
  float4v O[4];
#pragma unroll
  for (int s = 0; s < 4; ++s) O[s] = (float4v){0.f, 0.f, 0.f, 0.f};
#pragma unroll
  for (int chh = 0; chh < 8; ++chh) {
    const size_t ab = (size_t)(dw + lq) * CD + chh * 32 + quad * 8;
    short8v a0 = *(const short8v*)(Wpb + ab);
#pragma unroll
    for (int s = 0; s < 4; ++s) {
      const size_t bb = ((size_t)b * ND + n0 + s * 16 + lq) * CD + chh * 32 + quad * 8;
      short8v bv = *(const short8v*)(y + bb);
      O[s] = mfma16(a0, bv, O[s]);
    }
  }
#pragma unroll
  for (int r = 0; r < 4; ++r) {
    const int d = dw + quad * 4 + r;
    const float inv  = gamma[d] / sqrtf(var[d] + 1e-5f);
    const float bias = beta[d] - mean[d] * inv;
#pragma unroll
    for (int s = 0; s < 4; ++s) {
      const int n = n0 + s * 16 + lq;
      const size_t oi = ((size_t)b * CD + d) * ND + n;
      out[oi] = fmaxf(O[s][r] * inv + bias, 0.f) + x[oi];
    }
  }
}

extern "C" void kernel_launch(void* const* d_in, const int* in_sizes, int n_in,
                              void* d_out, int out_size, void* d_ws, size_t ws_size,
                              hipStream_t stream) {
  const float* x     = (const float*)d_in[0];
  const float* Wq    = (const float*)d_in[1];
  const float* Wk    = (const float*)d_in[2];
  const float* Wv    = (const float*)d_in[3];
  const float* Wp    = (const float*)d_in[4];
  const float* gamma = (const float*)d_in[5];
  const float* beta  = (const float*)d_in[6];
  const float* mean  = (const float*)d_in[7];
  const float* var   = (const float*)d_in[8];
  float* out = (float*)d_out;

  char* wsp = (char*)d_ws;
  unsigned short* qhp = (unsigned short*)wsp; wsp += (size_t)BD * ND * DA * 2;
  unsigned short* khp = (unsigned short*)wsp; wsp += (size_t)BD * ND * DA * 2;
  unsigned short* klp = (unsigned short*)wsp; wsp += (size_t)BD * ND * DA * 2;
  unsigned short* vT  = (unsigned short*)wsp; wsp += (size_t)BD * CD * ND * 2;
  unsigned short* xTh = (unsigned short*)wsp; wsp += (size_t)BD * ND * CD * 2;  // aliased as y
  unsigned short* xTl = (unsigned short*)wsp; wsp += (size_t)BD * ND * CD * 2;
  unsigned short* Wch = (unsigned short*)wsp; wsp += (size_t)384 * 256 * 2;
  unsigned short* Wcl = (unsigned short*)wsp; wsp += (size_t)384 * 256 * 2;
  unsigned short* Wph = (unsigned short*)wsp; wsp += (size_t)256 * 256 * 2;
  unsigned short* Wpl = (unsigned short*)wsp; wsp += (size_t)256 * 256 * 2;
  float* Drec = (float*)wsp; wsp += (size_t)BD * ND * 4;
  float* Dp   = (float*)wsp; wsp += (size_t)2 * BD * ND * 4;
  unsigned short* y = xTh;  // xTh consumed+overwritten by k_attn epilogue

  dim3 blk(256), blk5(512);
  k_prep<<<dim3(ND / 64, CD / 64, BD), blk, 0, stream>>>(x, xTh, xTl);
  k_prepW<<<dim3(160), blk, 0, stream>>>(Wq, Wk, Wv, Wp, Wch, Wcl, Wph, Wpl);
  k_proj<<<dim3(ND / 128, BD), blk5, 0, stream>>>(xTh, xTl, Wch, Wcl, qhp, khp,
                                                  klp, vT);
  k_colsum<<<dim3(512), blk5, 0, stream>>>(qhp, khp, klp, Dp);
  k_rcp<<<dim3(32), blk, 0, stream>>>(Dp, Drec);
  k_attn<<<dim3(256), blk5, 0, stream>>>(qhp, khp, klp, vT, Drec, y, xTl);
  k_final<<<dim3(2048), blk, 0, stream>>>(y, Wph, x, gamma, beta, mean, var, out);
}